// Round 12
// baseline (713.141 us; speedup 1.0000x reference)
//
#include <hip/hip_runtime.h>
#include <stdint.h>

// GLA block for MI355X (gfx950).
// B=8 S=2048 D=1024 H=4 DK=128 DV=256 CHUNK=64 (32 chunks), MLP_H=4096.
// R12: GEMM -> 128x256 tile, 8 waves, BK=32, 48 KiB LDS dbuf => 2 blocks/CU
// (16 waves/CU in 2 INDEPENDENT barrier groups; R11 had 16 waves lockstepped
// in one block). vmcnt(3) counted prefetch; 2-way-free slot swizzle
// (slot ^= (row>>1)&3) on staging source + ds_read.

typedef unsigned short u16t;
typedef __attribute__((ext_vector_type(8))) short bf16x8;
typedef __attribute__((ext_vector_type(4))) float f32x4;
typedef __attribute__((ext_vector_type(4))) unsigned short u16x4;

__device__ __forceinline__ float bf2f(unsigned short u){ union{unsigned int i; float f;} v; v.i=((unsigned int)u)<<16; return v.f; }
__device__ __forceinline__ unsigned short f2bf(float f){ union{unsigned int i; float f;} v; v.f=f; unsigned int r=v.i+0x7FFFu+((v.i>>16)&1u); return (unsigned short)(r>>16); }
__device__ __forceinline__ f32x4 cvt4(u16x4 u){ f32x4 r; r[0]=bf2f(u[0]); r[1]=bf2f(u[1]); r[2]=bf2f(u[2]); r[3]=bf2f(u[3]); return r; }

// fast tanh-GELU (native exp2/rcp); |err| vs exact-erf gelu ~3e-4.
__device__ __forceinline__ float gelu_f(float t){
  const float t3 = t*t*t;
  const float y = 2.3021183f*t + 0.10295465f*t3;
  const float e = __builtin_amdgcn_exp2f(y);
  return t - t*__builtin_amdgcn_rcpf(e + 1.f);
}

__device__ __forceinline__ void gload_lds16(const unsigned short* g, unsigned short* l)
{
  __builtin_amdgcn_global_load_lds(
      (const __attribute__((address_space(1))) unsigned int*)g,
      (__attribute__((address_space(3))) unsigned int*)l,
      16, 0, 0);
}

// ---------------- merged transpose f32 [Kin][N] -> bf16 [N][Kin], 7 weights ----------------
__global__ void k_transpose_multi(const float* __restrict__ Wq, const float* __restrict__ Wk,
                                  const float* __restrict__ Wv, const float* __restrict__ Wg,
                                  const float* __restrict__ Wo, const float* __restrict__ W1,
                                  const float* __restrict__ W2,
                                  unsigned short* __restrict__ WPT, unsigned short* __restrict__ WOT,
                                  unsigned short* __restrict__ W1T, unsigned short* __restrict__ W2T)
{
  __shared__ float tile[32][33];
  int bid = blockIdx.x;
  const float* src; unsigned short* dst; int Kin, N, nx;
  if      (bid < 512)  { src=Wq; dst=WPT;                          Kin=1024; N=512;  nx=16;  }
  else if (bid < 1024) { src=Wk; dst=WPT+(size_t)512*1024;         Kin=1024; N=512;  nx=16;  bid-=512;  }
  else if (bid < 2048) { src=Wv; dst=WPT+(size_t)1024*1024;        Kin=1024; N=1024; nx=32;  bid-=1024; }
  else if (bid < 3072) { src=Wg; dst=WPT+(size_t)2048*1024;        Kin=1024; N=1024; nx=32;  bid-=2048; }
  else if (bid < 4096) { src=Wo; dst=WOT;                          Kin=1024; N=1024; nx=32;  bid-=3072; }
  else if (bid < 8192) { src=W1; dst=W1T;                          Kin=1024; N=4096; nx=128; bid-=4096; }
  else                 { src=W2; dst=W2T;                          Kin=4096; N=1024; nx=32;  bid-=8192; }
  const int n0 = (bid % nx)*32, k0 = (bid / nx)*32;
  const int tx = threadIdx.x, ty = threadIdx.y;
  #pragma unroll
  for (int i = 0; i < 4; ++i)
    tile[ty + i*8][tx] = src[(size_t)(k0 + ty + i*8)*N + n0 + tx];
  __syncthreads();
  #pragma unroll
  for (int i = 0; i < 4; ++i)
    dst[(size_t)(n0 + ty + i*8)*Kin + k0 + tx] = f2bf(tile[tx][ty + i*8]);
}

// ---------------- Wgk = Wgk1[1024,16] @ Wgk2[16,512] -> bf16 transposed rows [512][1024] ----------------
__global__ void k_wgk(const float* __restrict__ Wgk1, const float* __restrict__ Wgk2, unsigned short* __restrict__ dstT)
{
  const int idx = blockIdx.x*256 + threadIdx.x;
  const int i = idx & 1023, j = idx >> 10;
  float s = 0.f;
  #pragma unroll
  for (int r = 0; r < 16; ++r) s += Wgk1[i*16 + r] * Wgk2[r*512 + j];
  dstT[(size_t)j*1024 + i] = f2bf(s);
}

// ---------------- V/K transpose: proj v-cols -> VT[bh][256][2048]; kt -> KTT[bh][128][2048] ----------------
__global__ void k_vtrans(const unsigned short* __restrict__ proj, const unsigned short* __restrict__ kt,
                         unsigned short* __restrict__ vtg, unsigned short* __restrict__ ktt)
{
  __shared__ unsigned short tile[32][33];
  const int tt = blockIdx.x, zz = blockIdx.y, bh = blockIdx.z;
  const int b = bh >> 2, h = bh & 3;
  const int tx = threadIdx.x, ty = threadIdx.y;
  if (zz < 8) {
    const int dvt = zz;
    #pragma unroll
    for (int i = 0; i < 4; ++i)
      tile[ty + i*8][tx] = proj[((size_t)b*2048 + tt*32 + ty + i*8)*3584 + 1024 + h*256 + dvt*32 + tx];
    __syncthreads();
    #pragma unroll
    for (int i = 0; i < 4; ++i)
      vtg[((size_t)bh*256 + dvt*32 + ty + i*8)*2048 + tt*32 + tx] = tile[tx][ty + i*8];
  } else {
    const int dkt = zz - 8;
    #pragma unroll
    for (int i = 0; i < 4; ++i)
      tile[ty + i*8][tx] = kt[((size_t)bh*2048 + tt*32 + ty + i*8)*128 + dkt*32 + tx];
    __syncthreads();
    #pragma unroll
    for (int i = 0; i < 4; ++i)
      ktt[((size_t)bh*128 + dkt*32 + ty + i*8)*2048 + tt*32 + tx] = tile[tx][ty + i*8];
  }
}

// ---------------- LayerNorm row=1024, f32 in -> bf16 out ----------------
__global__ __launch_bounds__(256) void k_layernorm(const float* __restrict__ x, const float* __restrict__ g,
                                                   const float* __restrict__ b, unsigned short* __restrict__ out)
{
  const int row = blockIdx.x, tid = threadIdx.x;
  const float4 xv = *(const float4*)&x[(size_t)row*1024 + tid*4];
  float s  = xv.x + xv.y + xv.z + xv.w;
  float sq = xv.x*xv.x + xv.y*xv.y + xv.z*xv.z + xv.w*xv.w;
  #pragma unroll
  for (int o = 32; o > 0; o >>= 1) { s += __shfl_xor(s, o); sq += __shfl_xor(sq, o); }
  __shared__ float red[8];
  const int w = tid >> 6;
  if ((tid & 63) == 0) { red[w] = s; red[4 + w] = sq; }
  __syncthreads();
  s  = red[0] + red[1] + red[2] + red[3];
  sq = red[4] + red[5] + red[6] + red[7];
  const float mu = s * (1.f/1024.f);
  const float var = sq * (1.f/1024.f) - mu*mu;
  const float rs = rsqrtf(var + 1e-5f);
  float xe[4] = {xv.x, xv.y, xv.z, xv.w};
  u16x4 o4;
  #pragma unroll
  for (int i = 0; i < 4; ++i) {
    const int c = tid*4 + i;
    o4[i] = f2bf((xe[i] - mu) * rs * g[c] + b[c]);
  }
  *(u16x4*)&out[(size_t)row*1024 + tid*4] = o4;
}

// ---------------- 128x256 8-wave bf16 MFMA GEMM: C = A[M,K] @ Bt[N,K]^T ----------------
// 512 threads = 8 waves (2wr x 4wc); wave tile 64x64 (4x4 frags), BK=32.
// LDS: 2 bufs x (A[128][32] 8KB + B[256][32] 16KB) = 48 KiB -> 2 blocks/CU.
// Slot swizzle: col8 ^= (row>>1)&3 (2-way free). vmcnt(3) counted prefetch.
// EPI: 0 = store bf16; 1 = +resid -> f32; 2 = +bias, gelu -> bf16; 3 = +bias +resid -> f32
template<int EPI>
__global__ __launch_bounds__(512, 4)
void gemm256(const unsigned short* __restrict__ A, const unsigned short* __restrict__ Bt,
             int N, int K,
             float* outF, unsigned short* outH,
             const float* resid, const float* bias)
{
  __shared__ __align__(16) unsigned short lds[24576];   // 48 KiB
  const int tid = threadIdx.x;
  const int lane = tid & 63, w = tid >> 6;
  const int wr = w >> 2, wc = w & 3;
  const int l15 = lane & 15, lq = lane >> 4;

  // bijective XCD-aware swizzle (m204)
  const int nwg = gridDim.x * gridDim.y;
  const int bid = blockIdx.y * gridDim.x + blockIdx.x;
  const int q = nwg >> 3, r = nwg & 7;
  const int xcd = bid & 7, lid = bid >> 3;
  const int sw = (xcd < r ? xcd*(q+1) : r*(q+1) + (xcd - r)*q) + lid;
  const int row0 = (sw / gridDim.x) * 128;
  const int col0 = (sw % gridDim.x) * 256;

  // staging: thread covers 16B: row = tid>>2 (0..127), slot = tid&3 (8 elems).
  // pre-swizzled global source col: (slot ^ ((row>>1)&3)) * 8.
  const int rowS = tid >> 2;
  const int csw  = ((tid & 3) ^ ((rowS >> 1) & 3)) * 8;
  const unsigned short* baseA    = A  + (size_t)(row0 + rowS) * K + csw;
  const unsigned short* baseB[2];
  #pragma unroll
  for (int L = 0; L < 2; ++L)
    baseB[L] = Bt + (size_t)(col0 + L*128 + rowS) * K + csw;

  const int NT = K >> 5;

  f32x4 acc[4][4];
  #pragma unroll
  for (int m = 0; m < 4; ++m)
    #pragma unroll
    for (int n = 0; n < 4; ++n) { acc[m][n][0]=0.f; acc[m][n][1]=0.f; acc[m][n][2]=0.f; acc[m][n][3]=0.f; }

  // read-side swizzle key: rows are base(mult of 16)+l15 -> (row>>1)&3 = (l15>>1)&3
  const int rk = (l15 >> 1) & 3;

  #define STAGE3(T)                                                            \
    {                                                                          \
      const int dbase = ((T) & 1) * 12288;                                     \
      const int kt2 = (T) << 5;                                                \
      gload_lds16(baseA    + kt2, (unsigned short*)&lds[dbase +        w*512]); \
      gload_lds16(baseB[0] + kt2, (unsigned short*)&lds[dbase + 4096 + w*512]); \
      gload_lds16(baseB[1] + kt2, (unsigned short*)&lds[dbase + 8192 + w*512]); \
    }

  STAGE3(0);
  for (int t = 0; t < NT; ++t) {
    const int dbase = (t & 1) * 12288;
    if (t + 1 < NT) {
      STAGE3(t + 1);
      asm volatile("s_waitcnt vmcnt(3)" ::: "memory");   // tile t's 3 loads landed
    } else {
      asm volatile("s_waitcnt vmcnt(0)" ::: "memory");
    }
    __builtin_amdgcn_sched_barrier(0);
    __builtin_amdgcn_s_barrier();          // tile t visible to all waves

    bf16x8 af[4], bfr[4];
    #pragma unroll
    for (int mm = 0; mm < 4; ++mm) {
      const int rA = wr*64 + mm*16 + l15;
      af[mm] = *(const bf16x8*)&lds[dbase + rA*32 + ((lq ^ rk) * 8)];
    }
    #pragma unroll
    for (int nn = 0; nn < 4; ++nn) {
      const int rB = wc*64 + nn*16 + l15;
      bfr[nn] = *(const bf16x8*)&lds[dbase + 4096 + rB*32 + ((lq ^ rk) * 8)];
    }
    asm volatile("s_waitcnt lgkmcnt(0)" ::: "memory");
    __builtin_amdgcn_sched_barrier(0);
    __builtin_amdgcn_s_setprio(1);
    #pragma unroll
    for (int mm = 0; mm < 4; ++mm)
      #pragma unroll
      for (int nn = 0; nn < 4; ++nn)
        acc[mm][nn] = __builtin_amdgcn_mfma_f32_16x16x32_bf16(af[mm], bfr[nn], acc[mm][nn], 0, 0, 0);
    __builtin_amdgcn_s_setprio(0);
    __builtin_amdgcn_s_barrier();          // WAR: done reading buf before overwrite
  }
  #undef STAGE3

  // epilogue
  #pragma unroll
  for (int mm = 0; mm < 4; ++mm)
    #pragma unroll
    for (int nn = 0; nn < 4; ++nn)
      #pragma unroll
      for (int ii = 0; ii < 4; ++ii) {
        const int rr = row0 + wr*64 + mm*16 + lq*4 + ii;
        const int cc = col0 + wc*64 + nn*16 + l15;
        const size_t idx = (size_t)rr * N + cc;
        const float v = acc[mm][nn][ii];
        if constexpr (EPI == 0) {
          outH[idx] = f2bf(v);
        } else if constexpr (EPI == 1) {
          outF[idx] = v + resid[idx];
        } else if constexpr (EPI == 2) {
          outH[idx] = f2bf(gelu_f(v + bias[cc]));
        } else {
          outF[idx] = v + bias[cc] + resid[idx];
        }
      }
}

// ---------------- scan prep: per (bh, chunk): cumsum gates, write qt/kt bf16, eac f32 ----------------
__global__ __launch_bounds__(128) void k_scanprep(const unsigned short* __restrict__ proj, const float* __restrict__ bgk,
                                                  unsigned short* __restrict__ qt, unsigned short* __restrict__ kt,
                                                  float* __restrict__ eac)
{
  const int c = blockIdx.x & 31, bh = blockIdx.x >> 5;
  const int b = bh >> 2, h = bh & 3;
  const int dk = threadIdx.x;
  const size_t tok0 = (size_t)b*2048 + c*64;
  const float bg = bgk[h*128 + dk];
  float A = 0.f, ea = 1.f;
  for (int t = 0; t < 64; ++t) {
    const size_t prow = (tok0 + t) * 3584;
    const float qv = bf2f(proj[prow + h*128 + dk]);
    const float kv = bf2f(proj[prow + 512 + h*128 + dk]);
    const float z = bf2f(proj[prow + 3072 + h*128 + dk]) + bg;
    const float az = fabsf(z);
    const float sp = fmaxf(-z, 0.f)
                   + 0.69314718f*__builtin_amdgcn_logf(1.f + __builtin_amdgcn_exp2f(-1.44269504f*az));
    A -= sp * 0.0625f;
    ea = __builtin_amdgcn_exp2f(A * 1.44269504f);
    const float em = __builtin_amdgcn_rcpf(ea);
    const size_t orow = ((size_t)bh*2048 + c*64 + t)*128 + dk;
    qt[orow] = f2bf(qv * ea * 0.08838834764831845f);
    kt[orow] = f2bf(kv * em);
  }
  eac[((size_t)bh*32 + c)*128 + dk] = ea;
}

// ---------------- MFMA chunk-state recurrence; stores S^T[dv][dk] at chunk START ----------------
__global__ __launch_bounds__(512) void k_seqstate(const unsigned short* __restrict__ ktt,
                                                  const unsigned short* __restrict__ vtg,
                                                  const float* __restrict__ eac,
                                                  unsigned short* __restrict__ sst)
{
  __shared__ __align__(16) unsigned short SLq[16384];
  const int bid = blockIdx.x;
  const int bh = bid >> 3, dks = (bid >> 2) & 1, dvs = bid & 3;
  const int tid = threadIdx.x, lane = tid & 63, w = tid >> 6;
  const int wr = w >> 2, wc = w & 3;
  const int l15 = lane & 15, lq = lane >> 4;
  const int kc8 = (lane & 7) * 8;

  #define SSTAGE(C, BUF)                                                        \
    { { const int o = w*512 + lane*8;                                           \
        const int dkl = o >> 6;                                                 \
        gload_lds16(&ktt[((size_t)bh*128 + dks*64 + dkl)*2048 + (C)*64 + (kc8 ^ ((dkl & 7) << 3))], \
                    (unsigned short*)&SLq[(BUF)*8192 + w*512]); }                \
      { const int o = w*512 + lane*8;                                           \
        const int dvl = o >> 6;                                                 \
        gload_lds16(&vtg[((size_t)bh*256 + dvs*64 + dvl)*2048 + (C)*64 + (kc8 ^ ((dvl & 7) << 3))], \
                    (unsigned short*)&SLq[(BUF)*8192 + 4096 + w*512]); } }

  f32x4 acc[2];
  acc[0][0]=0.f; acc[0][1]=0.f; acc[0][2]=0.f; acc[0][3]=0.f;
  acc[1] = acc[0];

  SSTAGE(0, 0);
  asm volatile("s_waitcnt vmcnt(0)" ::: "memory");
  __builtin_amdgcn_sched_barrier(0);
  __builtin_amdgcn_s_barrier();

  for (int c = 0; c < 32; ++c) {
    const int buf = c & 1;
    if (c + 1 < 32) {
      SSTAGE(c + 1, buf ^ 1);
      asm volatile("s_waitcnt vmcnt(2)" ::: "memory");
    } else {
      asm volatile("s_waitcnt vmcnt(0)" ::: "memory");
    }
    __builtin_amdgcn_sched_barrier(0);
    __builtin_amdgcn_s_barrier();

    const size_t srow = (((size_t)bh*32 + c)*256 + dvs*64 + wc*16 + l15)*128;
    #pragma unroll
    for (int mm = 0; mm < 2; ++mm) {
      u16x4 tj;
      tj[0]=f2bf(acc[mm][0]); tj[1]=f2bf(acc[mm][1]); tj[2]=f2bf(acc[mm][2]); tj[3]=f2bf(acc[mm][3]);
      *(u16x4*)&sst[srow + dks*64 + wr*32 + mm*16 + lq*4] = tj;
    }
    f32x4 ev[2];
    #pragma unroll
    for (int mm = 0; mm < 2; ++mm)
      ev[mm] = *(const f32x4*)&eac[(size_t)(bh*32 + c)*128 + dks*64 + wr*32 + mm*16 + lq*4];

    const int base = buf*8192;
    bf16x8 afr[2][2], bfrg[2];
    #pragma unroll
    for (int mm = 0; mm < 2; ++mm) {
      const int rl = wr*32 + mm*16 + l15;
      const int co = (rl & 7) << 3;
      afr[mm][0] = *(const bf16x8*)&SLq[base + rl*64 + ((lq*8) ^ co)];
      afr[mm][1] = *(const bf16x8*)&SLq[base + rl*64 + ((32 + lq*8) ^ co)];
    }
    {
      const int dvl = wc*16 + l15;
      const int co = (dvl & 7) << 3;
      bfrg[0] = *(const bf16x8*)&SLq[base + 4096 + dvl*64 + ((lq*8) ^ co)];
      bfrg[1] = *(const bf16x8*)&SLq[base + 4096 + dvl*64 + ((32 + lq*8) ^ co)];
    }
    asm volatile("s_waitcnt lgkmcnt(0)" ::: "memory");
    __builtin_amdgcn_sched_barrier(0);
    #pragma unroll
    for (int k4 = 0; k4 < 2; ++k4)
      #pragma unroll
      for (int mm = 0; mm < 2; ++mm)
        acc[mm] = __builtin_amdgcn_mfma_f32_16x16x32_bf16(afr[mm][k4], bfrg[k4], acc[mm], 0, 0, 0);
    #pragma unroll
    for (int mm = 0; mm < 2; ++mm)
      #pragma unroll
      for (int i = 0; i < 4; ++i)
        acc[mm][i] *= ev[mm][i];
    __builtin_amdgcn_s_barrier();
  }
  #undef SSTAGE
}

// ---------------- fused MFMA attn out: P=tril(QK^T); O=P@V+Q@S0; rmsnorm*g*sig(g) -> og ----------------
__global__ __launch_bounds__(512) void k_attn_out(const unsigned short* __restrict__ qt,
                                                  const unsigned short* __restrict__ kt,
                                                  const unsigned short* __restrict__ vtg,
                                                  const unsigned short* __restrict__ sst,
                                                  const unsigned short* __restrict__ proj,
                                                  const float* __restrict__ gnw,
                                                  unsigned short* __restrict__ og)
{
  __shared__ __align__(16) unsigned short SL[61440];
  __shared__ float ssq[64];
  const int c = blockIdx.x & 31, bh = blockIdx.x >> 5;
  const int b = bh >> 2, h = bh & 3;
  const int tid = threadIdx.x, lane = tid & 63, w = tid >> 6;
  const int wr = w >> 2, wc = w & 3;
  const int l15 = lane & 15, lq = lane >> 4;
  const size_t qk0 = (size_t)bh*2048 + c*64;
  const size_t tok0 = (size_t)b*2048 + c*64;
  const int key15 = (l15 & 7) << 3;

  if (tid < 64) ssq[tid] = 0.f;

  const int kc8 = (lane & 7) * 8;
  #pragma unroll
  for (int it = 0; it < 2; ++it) {
    const int o = it*4096 + w*512 + lane*8;
    const int ch = o >> 12, r = (o >> 6) & 63;
    gload_lds16(&kt[(qk0 + r)*128 + ch*64 + (kc8 ^ ((r & 7) << 3))],
                (unsigned short*)&SL[53248 + it*4096 + w*512]);
  }
  #pragma unroll
  for (int it = 0; it < 4; ++it) {
    const int o = it*4096 + w*512 + lane*8;
    const int dv = o >> 6;
    gload_lds16(&vtg[((size_t)bh*256 + dv)*2048 + c*64 + (kc8 ^ ((dv & 7) << 3))],
                (unsigned short*)&SL[4096 + it*4096 + w*512]);
  }
  #pragma unroll
  for (int it = 0; it < 8; ++it) {
    const int o = it*4096 + w*512 + lane*8;
    const int ch = o >> 14, dv = (o >> 6) & 255;
    gload_lds16(&sst[((size_t)(bh*32 + c)*256 + dv)*128 + ch*64 + (kc8 ^ ((dv & 7) << 3))],
                (unsigned short*)&SL[20480 + it*4096 + w*512]);
  }
  bf16x8 aq[2][4];
  #pragma unroll
  for (int mm = 0; mm < 2; ++mm)
    #pragma unroll
    for (int k4 = 0; k4 < 4; ++k4)
      aq[mm][k4] = *(const bf16x8*)&qt[(qk0 + wr*32 + mm*16 + l15)*128 + k4*32 + lq*8];

  __syncthreads();

  f32x4 accp[2];
  accp[0][0]=0.f; accp[0][1]=0.f; accp[0][2]=0.f; accp[0][3]=0.f;
  accp[1] = accp[0];
  #pragma unroll
  for (int k4 = 0; k4 < 4; ++k4) {
    const int ch = k4 >> 1, k0c = (k4 & 1) * 32;
    const bf16x8 bk = *(const bf16x8*)&SL[53248 + ch*4096 + (wc*16 + l15)*64 + ((k0c + lq*8) ^ key15)];
    accp[0] = __builtin_amdgcn_mfma_f32_16x16x32_bf16(aq[0][k4], bk, accp[0], 0, 0, 0);
    accp[1] = __builtin_amdgcn_mfma_f32_16x16x32_bf16(aq[1][k4], bk, accp[1], 0, 0, 0);
  }
  #pragma unroll
  for (int mm = 0; mm < 2; ++mm)
    #pragma unroll
    for (int i = 0; i < 4; ++i) {
      const int rg = wr*32 + mm*16 + lq*4 + i;
      const int cg = wc*16 + l15;
      SL[rg*64 + (cg ^ ((rg & 7) << 3))] = f2bf((cg <= rg) ? accp[mm][i] : 0.f);
    }
  __syncthreads();

  f32x4 acco[2][4];
  #pragma unroll
  for (int mm = 0; mm < 2; ++mm)
    #pragma unroll
    for (int nn = 0; nn < 4; ++nn) { acco[mm][nn][0]=0.f; acco[mm][nn][1]=0.f; acco[mm][nn][2]=0.f; acco[mm][nn][3]=0.f; }

  #pragma unroll
  for (int t4 = 0; t4 < 2; ++t4) {
    bf16x8 ap[2];
    #pragma unroll
    for (int mm = 0; mm < 2; ++mm) {
      const int r = wr*32 + mm*16 + l15;
      ap[mm] = *(const bf16x8*)&SL[r*64 + ((t4*32 + lq*8) ^ key15)];
    }
    #pragma unroll
    for (int nn = 0; nn < 4; ++nn) {
      const int dv = wc*64 + nn*16 + l15;
      const bf16x8 bv = *(const bf16x8*)&SL[4096 + dv*64 + ((t4*32 + lq*8) ^ key15)];
      acco[0][nn] = __builtin_amdgcn_mfma_f32_16x16x32_bf16(ap[0], bv, acco[0][nn], 0, 0, 0);
      acco[1][nn] = __builtin_amdgcn_mfma_f32_16x16x32_bf16(ap[1], bv, acco[1][nn], 0, 0, 0);
    }
  }
  #pragma unroll
  for (int k4 = 0; k4 < 4; ++k4) {
    const int ch = k4 >> 1, k0c = (k4 & 1) * 32;
    #pragma unroll
    for (int nn = 0; nn < 4; ++nn) {
      const int dv = wc*64 + nn*16 + l15;
      const bf16x8 bs = *(const bf16x8*)&SL[20480 + ch*16384 + dv*64 + ((k0c + lq*8) ^ key15)];
      acco[0][nn] = __builtin_amdgcn_mfma_f32_16x16x32_bf16(aq[0][k4], bs, acco[0][nn], 0, 0, 0);
      acco[1][nn] = __builtin_amdgcn_mfma_f32_16x16x32_bf16(aq[1][k4], bs, acco[1][nn], 0, 0, 0);
    }
  }

  #pragma unroll
  for (int mm = 0; mm < 2; ++mm) {
    float part[4];
    #pragma unroll
    for (int i = 0; i < 4; ++i) {
      float s = 0.f;
      #pragma unroll
      for (int nn = 0; nn < 4; ++nn) s += acco[mm][nn][i]*acco[mm][nn][i];
      s += __shfl_xor(s, 1); s += __shfl_xor(s, 2); s += __shfl_xor(s, 4); s += __shfl_xor(s, 8);
      part[i] = s;
    }
    if (l15 == 0) {
      #pragma unroll
      for (int i = 0; i < 4; ++i)
        atomicAdd(&ssq[wr*32 + mm*16 + lq*4 + i], part[i]);
    }
  }
  __syncthreads();

  #pragma unroll
  for (int mm = 0; mm < 2; ++mm)
    #pragma unroll
    for (int i = 0; i < 4; ++i) {
      const int rg = wr*32 + mm*16 + lq*4 + i;
      const float rs = rsqrtf(ssq[rg] * (1.f/256.f) + 1e-5f);
      const size_t token = tok0 + rg;
      #pragma unroll
      for (int nn = 0; nn < 4; ++nn) {
        const int dv = wc*64 + nn*16 + l15;
        const float gf = bf2f(proj[token*3584 + 2048 + h*256 + dv]);
        const float swv = gf * __builtin_amdgcn_rcpf(1.f + __builtin_amdgcn_exp2f(-1.44269504f*gf));
        og[token*1024 + h*256 + dv] = f2bf(acco[mm][nn][i] * rs * gnw[dv] * swv);
      }
    }
}

extern "C" void kernel_launch(void* const* d_in, const int* in_sizes, int n_in,
                              void* d_out, int out_size, void* d_ws, size_t ws_size,
                              hipStream_t stream)
{
  (void)in_sizes; (void)n_in; (void)out_size; (void)ws_size;
  const float* x    = (const float*)d_in[0];
  const float* ln1g = (const float*)d_in[1];
  const float* ln1b = (const float*)d_in[2];
  const float* Wq   = (const float*)d_in[3];
  const float* Wk   = (const float*)d_in[4];
  const float* Wv   = (const float*)d_in[5];
  const float* Wg   = (const float*)d_in[6];
  const float* Wgk1 = (const float*)d_in[7];
  const float* Wgk2 = (const float*)d_in[8];
  const float* bgk  = (const float*)d_in[9];
  const float* gnw  = (const float*)d_in[10];
  const float* Wo   = (const float*)d_in[11];
  const float* ln2g = (const float*)d_in[12];
  const float* ln2b = (const float*)d_in[13];
  const float* W1   = (const float*)d_in[14];
  const float* b1   = (const float*)d_in[15];
  const float* W2   = (const float*)d_in[16];
  const float* b2   = (const float*)d_in[17];
  float* out = (float*)d_out;
  char* ws = (char*)d_ws;

  u16t*  XN   = (u16t*)(ws + 0);
  u16t*  KTT  = (u16t*)(ws + 0);
  u16t*  OG   = (u16t*)(ws + 0);
  u16t*  WPT  = (u16t*)(ws + 33554432);
  u16t*  WOT  = (u16t*)(ws + 40894464);
  u16t*  W1T  = (u16t*)(ws + 42991616);
  u16t*  W2T  = (u16t*)(ws + 51380224);
  u16t*  PROJ = (u16t*)(ws + 59768832);
  u16t*  QT   = (u16t*)(ws + 177209344);
  u16t*  KT   = (u16t*)(ws + 193986560);
  float* EAC  = (float*)(ws + 210763776);
  u16t*  VT   = (u16t*)(ws + 211288064);
  u16t*  H2   = (u16t*)(ws + 211288064);
  u16t*  HID  = PROJ;
  u16t*  SST  = (u16t*)d_out;

  k_transpose_multi<<<12288, dim3(32,8), 0, stream>>>(Wq, Wk, Wv, Wg, Wo, W1, W2, WPT, WOT, W1T, W2T);
  k_wgk<<<2048, 256, 0, stream>>>(Wgk1, Wgk2, WPT + (size_t)3072*1024);

  k_layernorm<<<16384, 256, 0, stream>>>(x, ln1g, ln1b, XN);
  gemm256<0><<<dim3(14,128), 512, 0, stream>>>(XN, WPT, 3584, 1024, nullptr, PROJ, nullptr, nullptr);
  k_scanprep<<<1024, 128, 0, stream>>>(PROJ, bgk, QT, KT, EAC);
  k_vtrans<<<dim3(64,12,32), dim3(32,8), 0, stream>>>(PROJ, KT, VT, KTT);
  k_seqstate<<<256, 512, 0, stream>>>(KTT, VT, EAC, SST);
  k_attn_out<<<1024, 512, 0, stream>>>(QT, KT, VT, SST, PROJ, gnw, OG);
  gemm256<1><<<dim3(4,128),  512, 0, stream>>>(OG, WOT, 1024, 1024, out, nullptr, x, nullptr);   // x1 = o@Wo + x
  k_layernorm<<<16384, 256, 0, stream>>>(out, ln2g, ln2b, H2);
  gemm256<2><<<dim3(16,128), 512, 0, stream>>>(H2, W1T, 4096, 1024, nullptr, HID, nullptr, b1);  // gelu(h@W1+b1)
  gemm256<3><<<dim3(4,128),  512, 0, stream>>>(HID, W2T, 1024, 4096, out, nullptr, out, b2);     // out = x1 + hid@W2 + b2
}

// Round 13
// 676.223 us; speedup vs baseline: 1.0546x; 1.0546x over previous
//
#include <hip/hip_runtime.h>
#include <stdint.h>

// GLA block for MI355X (gfx950).
// B=8 S=2048 D=1024 H=4 DK=128 DV=256 CHUNK=64 (32 chunks), MLP_H=4096.
// R13: GEMM reverted to R11 16-wave 256^2 (best measured: 155us/880TF, at the
// m248 shape-ceiling reference). gk low-rank path pulled out of proj GEMM:
// k_zgemm (XN@Wgk1 -> ZG f32) + ZG@Wgk2+bgk folded into k_scanprep.
// Proj GEMM N=3584->3072 (grid 12x64 = exactly 3 rounds of 256 CUs).

typedef unsigned short u16t;
typedef __attribute__((ext_vector_type(8))) short bf16x8;
typedef __attribute__((ext_vector_type(4))) float f32x4;
typedef __attribute__((ext_vector_type(4))) unsigned short u16x4;

__device__ __forceinline__ float bf2f(unsigned short u){ union{unsigned int i; float f;} v; v.i=((unsigned int)u)<<16; return v.f; }
__device__ __forceinline__ unsigned short f2bf(float f){ union{unsigned int i; float f;} v; v.f=f; unsigned int r=v.i+0x7FFFu+((v.i>>16)&1u); return (unsigned short)(r>>16); }
__device__ __forceinline__ f32x4 cvt4(u16x4 u){ f32x4 r; r[0]=bf2f(u[0]); r[1]=bf2f(u[1]); r[2]=bf2f(u[2]); r[3]=bf2f(u[3]); return r; }

// fast tanh-GELU (native exp2/rcp); |err| vs exact-erf gelu ~3e-4.
__device__ __forceinline__ float gelu_f(float t){
  const float t3 = t*t*t;
  const float y = 2.3021183f*t + 0.10295465f*t3;
  const float e = __builtin_amdgcn_exp2f(y);
  return t - t*__builtin_amdgcn_rcpf(e + 1.f);
}

__device__ __forceinline__ void gload_lds16(const unsigned short* g, unsigned short* l)
{
  __builtin_amdgcn_global_load_lds(
      (const __attribute__((address_space(1))) unsigned int*)g,
      (__attribute__((address_space(3))) unsigned int*)l,
      16, 0, 0);
}

// ---------------- merged transpose f32 [Kin][N] -> bf16 [N][Kin], 7 weights ----------------
__global__ void k_transpose_multi(const float* __restrict__ Wq, const float* __restrict__ Wk,
                                  const float* __restrict__ Wv, const float* __restrict__ Wg,
                                  const float* __restrict__ Wo, const float* __restrict__ W1,
                                  const float* __restrict__ W2,
                                  unsigned short* __restrict__ WPT, unsigned short* __restrict__ WOT,
                                  unsigned short* __restrict__ W1T, unsigned short* __restrict__ W2T)
{
  __shared__ float tile[32][33];
  int bid = blockIdx.x;
  const float* src; unsigned short* dst; int Kin, N, nx;
  if      (bid < 512)  { src=Wq; dst=WPT;                          Kin=1024; N=512;  nx=16;  }
  else if (bid < 1024) { src=Wk; dst=WPT+(size_t)512*1024;         Kin=1024; N=512;  nx=16;  bid-=512;  }
  else if (bid < 2048) { src=Wv; dst=WPT+(size_t)1024*1024;        Kin=1024; N=1024; nx=32;  bid-=1024; }
  else if (bid < 3072) { src=Wg; dst=WPT+(size_t)2048*1024;        Kin=1024; N=1024; nx=32;  bid-=2048; }
  else if (bid < 4096) { src=Wo; dst=WOT;                          Kin=1024; N=1024; nx=32;  bid-=3072; }
  else if (bid < 8192) { src=W1; dst=W1T;                          Kin=1024; N=4096; nx=128; bid-=4096; }
  else                 { src=W2; dst=W2T;                          Kin=4096; N=1024; nx=32;  bid-=8192; }
  const int n0 = (bid % nx)*32, k0 = (bid / nx)*32;
  const int tx = threadIdx.x, ty = threadIdx.y;
  #pragma unroll
  for (int i = 0; i < 4; ++i)
    tile[ty + i*8][tx] = src[(size_t)(k0 + ty + i*8)*N + n0 + tx];
  __syncthreads();
  #pragma unroll
  for (int i = 0; i < 4; ++i)
    dst[(size_t)(n0 + ty + i*8)*Kin + k0 + tx] = f2bf(tile[tx][ty + i*8]);
}

// ---------------- ZG = XN @ Wgk1 : [16384][16] f32 ----------------
// block = 16 tokens x 16 j (256 thr); chunked LDS (128 c at a time).
__global__ __launch_bounds__(256) void k_zgemm(const unsigned short* __restrict__ XN,
                                               const float* __restrict__ Wgk1,
                                               float* __restrict__ zg)
{
  __shared__ float Wg1s[128*16];          // 8 KB
  __shared__ unsigned short XNs[16*136];  // padded rows (136) for bank spread
  const int token0 = blockIdx.x * 16;
  const int tid = threadIdx.x;
  const int tt = tid >> 4, j = tid & 15;
  float acc = 0.f;
  for (int cb = 0; cb < 8; ++cb) {
    __syncthreads();
    #pragma unroll
    for (int i = 0; i < 8; ++i)
      Wg1s[i*256 + tid] = Wgk1[(size_t)cb*2048 + i*256 + tid];
    {
      const int r = tid >> 4, cc = (tid & 15) * 8;
      *(u16x4*)&XNs[r*136 + cc]     = *(const u16x4*)&XN[(size_t)(token0 + r)*1024 + cb*128 + cc];
      *(u16x4*)&XNs[r*136 + cc + 4] = *(const u16x4*)&XN[(size_t)(token0 + r)*1024 + cb*128 + cc + 4];
    }
    __syncthreads();
    #pragma unroll 4
    for (int c = 0; c < 128; ++c)
      acc += bf2f(XNs[tt*136 + c]) * Wg1s[c*16 + j];
  }
  zg[(size_t)(token0 + tt)*16 + j] = acc;
}

// ---------------- V/K transpose: proj v-cols -> VT[bh][256][2048]; kt -> KTT[bh][128][2048] ----------------
__global__ void k_vtrans(const unsigned short* __restrict__ proj, const unsigned short* __restrict__ kt,
                         unsigned short* __restrict__ vtg, unsigned short* __restrict__ ktt)
{
  __shared__ unsigned short tile[32][33];
  const int tt = blockIdx.x, zz = blockIdx.y, bh = blockIdx.z;
  const int b = bh >> 2, h = bh & 3;
  const int tx = threadIdx.x, ty = threadIdx.y;
  if (zz < 8) {
    const int dvt = zz;
    #pragma unroll
    for (int i = 0; i < 4; ++i)
      tile[ty + i*8][tx] = proj[((size_t)b*2048 + tt*32 + ty + i*8)*3072 + 1024 + h*256 + dvt*32 + tx];
    __syncthreads();
    #pragma unroll
    for (int i = 0; i < 4; ++i)
      vtg[((size_t)bh*256 + dvt*32 + ty + i*8)*2048 + tt*32 + tx] = tile[tx][ty + i*8];
  } else {
    const int dkt = zz - 8;
    #pragma unroll
    for (int i = 0; i < 4; ++i)
      tile[ty + i*8][tx] = kt[((size_t)bh*2048 + tt*32 + ty + i*8)*128 + dkt*32 + tx];
    __syncthreads();
    #pragma unroll
    for (int i = 0; i < 4; ++i)
      ktt[((size_t)bh*128 + dkt*32 + ty + i*8)*2048 + tt*32 + tx] = tile[tx][ty + i*8];
  }
}

// ---------------- LayerNorm row=1024, f32 in -> bf16 out ----------------
__global__ __launch_bounds__(256) void k_layernorm(const float* __restrict__ x, const float* __restrict__ g,
                                                   const float* __restrict__ b, unsigned short* __restrict__ out)
{
  const int row = blockIdx.x, tid = threadIdx.x;
  const float4 xv = *(const float4*)&x[(size_t)row*1024 + tid*4];
  float s  = xv.x + xv.y + xv.z + xv.w;
  float sq = xv.x*xv.x + xv.y*xv.y + xv.z*xv.z + xv.w*xv.w;
  #pragma unroll
  for (int o = 32; o > 0; o >>= 1) { s += __shfl_xor(s, o); sq += __shfl_xor(sq, o); }
  __shared__ float red[8];
  const int w = tid >> 6;
  if ((tid & 63) == 0) { red[w] = s; red[4 + w] = sq; }
  __syncthreads();
  s  = red[0] + red[1] + red[2] + red[3];
  sq = red[4] + red[5] + red[6] + red[7];
  const float mu = s * (1.f/1024.f);
  const float var = sq * (1.f/1024.f) - mu*mu;
  const float rs = rsqrtf(var + 1e-5f);
  float xe[4] = {xv.x, xv.y, xv.z, xv.w};
  u16x4 o4;
  #pragma unroll
  for (int i = 0; i < 4; ++i) {
    const int c = tid*4 + i;
    o4[i] = f2bf((xe[i] - mu) * rs * g[c] + b[c]);
  }
  *(u16x4*)&out[(size_t)row*1024 + tid*4] = o4;
}

// ---------------- 256x256 16-wave bf16 MFMA GEMM: C = A[M,K] @ Bt[N,K]^T (R11, best) ----------------
template<int EPI>
__global__ __launch_bounds__(1024, 3)
void gemm256(const unsigned short* __restrict__ A, const unsigned short* __restrict__ Bt,
             int N, int K,
             float* outF, unsigned short* outH,
             const float* resid, const float* bias)
{
  __shared__ __align__(16) unsigned short lds[65536];   // 128 KiB
  const int tid = threadIdx.x;
  const int lane = tid & 63, w = tid >> 6;
  const int wr = w >> 2, wc = w & 3;
  const int l15 = lane & 15, lq = lane >> 4;

  // bijective XCD-aware swizzle (m204)
  const int nwg = gridDim.x * gridDim.y;
  const int bid = blockIdx.y * gridDim.x + blockIdx.x;
  const int q = nwg >> 3, r = nwg & 7;
  const int xcd = bid & 7, lid = bid >> 3;
  const int sw = (xcd < r ? xcd*(q+1) : r*(q+1) + (xcd - r)*q) + lid;
  const int row0 = (sw / gridDim.x) * 256;
  const int col0 = (sw % gridDim.x) * 256;

  // staging: 1024 thr x 16B = one 16KB chunk (128 rows x 64 cols) per issue.
  const int rA_ = tid >> 3;
  const int cswz = 8 * ((tid & 7) ^ (rA_ & 7));
  const unsigned short* baseA[2];
  const unsigned short* baseB[2];
  #pragma unroll
  for (int h = 0; h < 2; ++h) {
    baseA[h] = A  + (size_t)(row0 + h*128 + rA_) * K + cswz;
    baseB[h] = Bt + (size_t)(col0 + h*128 + rA_) * K + cswz;
  }

  const int NT = K >> 6;

  f32x4 acc[4][4];
  #pragma unroll
  for (int m = 0; m < 4; ++m)
    #pragma unroll
    for (int n = 0; n < 4; ++n) { acc[m][n][0]=0.f; acc[m][n][1]=0.f; acc[m][n][2]=0.f; acc[m][n][3]=0.f; }

  const int carA = (wr >> 1) * 8192;
  const int carB = 16384 + (wc >> 1) * 8192;
  const int rowA = (wr & 1) * 64;
  const int rowB = (wc & 1) * 64;
  const int co = (l15 & 7) * 8;

  #define STAGE4(T)                                                            \
    {                                                                          \
      const int dbase = ((T) & 1) * 32768;                                     \
      const int ktt2 = (T) << 6;                                               \
      gload_lds16(baseA[0] + ktt2, (unsigned short*)&lds[dbase +         w*512]); \
      gload_lds16(baseA[1] + ktt2, (unsigned short*)&lds[dbase +  8192 + w*512]); \
      gload_lds16(baseB[0] + ktt2, (unsigned short*)&lds[dbase + 16384 + w*512]); \
      gload_lds16(baseB[1] + ktt2, (unsigned short*)&lds[dbase + 24576 + w*512]); \
    }

  #define MMAH(BUF, H)                                                         \
    {                                                                          \
      bf16x8 af[4], bfr[4];                                                    \
      _Pragma("unroll")                                                        \
      for (int mm = 0; mm < 4; ++mm)                                           \
        af[mm] = *(const bf16x8*)&lds[(BUF) + carA + (rowA + mm*16 + l15)*64   \
                                      + (((H)*32 + lq*8) ^ co)];               \
      _Pragma("unroll")                                                        \
      for (int nn = 0; nn < 4; ++nn)                                           \
        bfr[nn] = *(const bf16x8*)&lds[(BUF) + carB + (rowB + nn*16 + l15)*64  \
                                       + (((H)*32 + lq*8) ^ co)];              \
      asm volatile("s_waitcnt lgkmcnt(0)" ::: "memory");                       \
      __builtin_amdgcn_sched_barrier(0);                                       \
      if (H) { __builtin_amdgcn_s_barrier(); }  /* WAR: all reads of buf done */ \
      __builtin_amdgcn_s_setprio(1);                                           \
      _Pragma("unroll")                                                        \
      for (int mm = 0; mm < 4; ++mm)                                           \
        _Pragma("unroll")                                                      \
        for (int nn = 0; nn < 4; ++nn)                                         \
          acc[mm][nn] = __builtin_amdgcn_mfma_f32_16x16x32_bf16(               \
              af[mm], bfr[nn], acc[mm][nn], 0, 0, 0);                          \
      __builtin_amdgcn_s_setprio(0);                                           \
    }

  STAGE4(0);
  for (int t = 0; t < NT; ++t) {
    const int buf = (t & 1) * 32768;
    if (t + 1 < NT) {
      STAGE4(t + 1);
      asm volatile("s_waitcnt vmcnt(4)" ::: "memory");
    } else {
      asm volatile("s_waitcnt vmcnt(0)" ::: "memory");
    }
    __builtin_amdgcn_sched_barrier(0);
    __builtin_amdgcn_s_barrier();
    MMAH(buf, 0);
    MMAH(buf, 1);
  }
  #undef STAGE4
  #undef MMAH

  #pragma unroll
  for (int mm = 0; mm < 4; ++mm)
    #pragma unroll
    for (int nn = 0; nn < 4; ++nn)
      #pragma unroll
      for (int ii = 0; ii < 4; ++ii) {
        const int rr = row0 + wr*64 + mm*16 + lq*4 + ii;
        const int cc = col0 + wc*64 + nn*16 + l15;
        const size_t idx = (size_t)rr * N + cc;
        const float v = acc[mm][nn][ii];
        if constexpr (EPI == 0) {
          outH[idx] = f2bf(v);
        } else if constexpr (EPI == 1) {
          outF[idx] = v + resid[idx];
        } else if constexpr (EPI == 2) {
          outH[idx] = f2bf(gelu_f(v + bias[cc]));
        } else {
          outF[idx] = v + bias[cc] + resid[idx];
        }
      }
}

// ---------------- scan prep: z = ZG@Wgk2 + bgk (f32); cumsum gates; write qt/kt bf16, eac f32 ----------------
__global__ __launch_bounds__(128) void k_scanprep(const unsigned short* __restrict__ proj,
                                                  const float* __restrict__ zg,
                                                  const float* __restrict__ Wgk2,
                                                  const float* __restrict__ bgk,
                                                  unsigned short* __restrict__ qt, unsigned short* __restrict__ kt,
                                                  float* __restrict__ eac)
{
  __shared__ float ZGs[1024];   // 64 tokens x 16
  const int c = blockIdx.x & 31, bh = blockIdx.x >> 5;
  const int b = bh >> 2, h = bh & 3;
  const int dk = threadIdx.x;
  const size_t tok0 = (size_t)b*2048 + c*64;
  #pragma unroll
  for (int it = 0; it < 8; ++it)
    ZGs[it*128 + dk] = zg[tok0*16 + it*128 + dk];
  __syncthreads();

  const int col = h*128 + dk;
  const float bg = bgk[col];
  float w2[16];
  #pragma unroll
  for (int r2 = 0; r2 < 16; ++r2) w2[r2] = Wgk2[r2*512 + col];

  float A = 0.f, ea = 1.f;
  for (int t = 0; t < 64; ++t) {
    const size_t prow = (tok0 + t) * 3072;
    const float qv = bf2f(proj[prow + h*128 + dk]);
    const float kv = bf2f(proj[prow + 512 + h*128 + dk]);
    float z = bg;
    #pragma unroll
    for (int r2 = 0; r2 < 16; ++r2) z += ZGs[t*16 + r2] * w2[r2];
    const float az = fabsf(z);
    const float sp = fmaxf(-z, 0.f)
                   + 0.69314718f*__builtin_amdgcn_logf(1.f + __builtin_amdgcn_exp2f(-1.44269504f*az));
    A -= sp * 0.0625f;
    ea = __builtin_amdgcn_exp2f(A * 1.44269504f);
    const float em = __builtin_amdgcn_rcpf(ea);
    const size_t orow = ((size_t)bh*2048 + c*64 + t)*128 + dk;
    qt[orow] = f2bf(qv * ea * 0.08838834764831845f);
    kt[orow] = f2bf(kv * em);
  }
  eac[((size_t)bh*32 + c)*128 + dk] = ea;
}

// ---------------- MFMA chunk-state recurrence; stores S^T[dv][dk] at chunk START ----------------
__global__ __launch_bounds__(512) void k_seqstate(const unsigned short* __restrict__ ktt,
                                                  const unsigned short* __restrict__ vtg,
                                                  const float* __restrict__ eac,
                                                  unsigned short* __restrict__ sst)
{
  __shared__ __align__(16) unsigned short SLq[16384];
  const int bid = blockIdx.x;
  const int bh = bid >> 3, dks = (bid >> 2) & 1, dvs = bid & 3;
  const int tid = threadIdx.x, lane = tid & 63, w = tid >> 6;
  const int wr = w >> 2, wc = w & 3;
  const int l15 = lane & 15, lq = lane >> 4;
  const int kc8 = (lane & 7) * 8;

  #define SSTAGE(C, BUF)                                                        \
    { { const int o = w*512 + lane*8;                                           \
        const int dkl = o >> 6;                                                 \
        gload_lds16(&ktt[((size_t)bh*128 + dks*64 + dkl)*2048 + (C)*64 + (kc8 ^ ((dkl & 7) << 3))], \
                    (unsigned short*)&SLq[(BUF)*8192 + w*512]); }                \
      { const int o = w*512 + lane*8;                                           \
        const int dvl = o >> 6;                                                 \
        gload_lds16(&vtg[((size_t)bh*256 + dvs*64 + dvl)*2048 + (C)*64 + (kc8 ^ ((dvl & 7) << 3))], \
                    (unsigned short*)&SLq[(BUF)*8192 + 4096 + w*512]); } }

  f32x4 acc[2];
  acc[0][0]=0.f; acc[0][1]=0.f; acc[0][2]=0.f; acc[0][3]=0.f;
  acc[1] = acc[0];

  SSTAGE(0, 0);
  asm volatile("s_waitcnt vmcnt(0)" ::: "memory");
  __builtin_amdgcn_sched_barrier(0);
  __builtin_amdgcn_s_barrier();

  for (int c = 0; c < 32; ++c) {
    const int buf = c & 1;
    if (c + 1 < 32) {
      SSTAGE(c + 1, buf ^ 1);
      asm volatile("s_waitcnt vmcnt(2)" ::: "memory");
    } else {
      asm volatile("s_waitcnt vmcnt(0)" ::: "memory");
    }
    __builtin_amdgcn_sched_barrier(0);
    __builtin_amdgcn_s_barrier();

    const size_t srow = (((size_t)bh*32 + c)*256 + dvs*64 + wc*16 + l15)*128;
    #pragma unroll
    for (int mm = 0; mm < 2; ++mm) {
      u16x4 tj;
      tj[0]=f2bf(acc[mm][0]); tj[1]=f2bf(acc[mm][1]); tj[2]=f2bf(acc[mm][2]); tj[3]=f2bf(acc[mm][3]);
      *(u16x4*)&sst[srow + dks*64 + wr*32 + mm*16 + lq*4] = tj;
    }
    f32x4 ev[2];
    #pragma unroll
    for (int mm = 0; mm < 2; ++mm)
      ev[mm] = *(const f32x4*)&eac[(size_t)(bh*32 + c)*128 + dks*64 + wr*32 + mm*16 + lq*4];

    const int base = buf*8192;
    bf16x8 afr[2][2], bfrg[2];
    #pragma unroll
    for (int mm = 0; mm < 2; ++mm) {
      const int rl = wr*32 + mm*16 + l15;
      const int co2 = (rl & 7) << 3;
      afr[mm][0] = *(const bf16x8*)&SLq[base + rl*64 + ((lq*8) ^ co2)];
      afr[mm][1] = *(const bf16x8*)&SLq[base + rl*64 + ((32 + lq*8) ^ co2)];
    }
    {
      const int dvl = wc*16 + l15;
      const int co2 = (dvl & 7) << 3;
      bfrg[0] = *(const bf16x8*)&SLq[base + 4096 + dvl*64 + ((lq*8) ^ co2)];
      bfrg[1] = *(const bf16x8*)&SLq[base + 4096 + dvl*64 + ((32 + lq*8) ^ co2)];
    }
    asm volatile("s_waitcnt lgkmcnt(0)" ::: "memory");
    __builtin_amdgcn_sched_barrier(0);
    #pragma unroll
    for (int k4 = 0; k4 < 2; ++k4)
      #pragma unroll
      for (int mm = 0; mm < 2; ++mm)
        acc[mm] = __builtin_amdgcn_mfma_f32_16x16x32_bf16(afr[mm][k4], bfrg[k4], acc[mm], 0, 0, 0);
    #pragma unroll
    for (int mm = 0; mm < 2; ++mm)
      #pragma unroll
      for (int i = 0; i < 4; ++i)
        acc[mm][i] *= ev[mm][i];
    __builtin_amdgcn_s_barrier();
  }
  #undef SSTAGE
}

// ---------------- fused MFMA attn out: P=tril(QK^T); O=P@V+Q@S0; rmsnorm*g*sig(g) -> og ----------------
__global__ __launch_bounds__(512) void k_attn_out(const unsigned short* __restrict__ qt,
                                                  const unsigned short* __restrict__ kt,
                                                  const unsigned short* __restrict__ vtg,
                                                  const unsigned short* __restrict__ sst,
                                                  const unsigned short* __restrict__ proj,
                                                  const float* __restrict__ gnw,
                                                  unsigned short* __restrict__ og)
{
  __shared__ __align__(16) unsigned short SL[61440];
  __shared__ float ssq[64];
  const int c = blockIdx.x & 31, bh = blockIdx.x >> 5;
  const int b = bh >> 2, h = bh & 3;
  const int tid = threadIdx.x, lane = tid & 63, w = tid >> 6;
  const int wr = w >> 2, wc = w & 3;
  const int l15 = lane & 15, lq = lane >> 4;
  const size_t qk0 = (size_t)bh*2048 + c*64;
  const size_t tok0 = (size_t)b*2048 + c*64;
  const int key15 = (l15 & 7) << 3;

  if (tid < 64) ssq[tid] = 0.f;

  const int kc8 = (lane & 7) * 8;
  #pragma unroll
  for (int it = 0; it < 2; ++it) {
    const int o = it*4096 + w*512 + lane*8;
    const int ch = o >> 12, r = (o >> 6) & 63;
    gload_lds16(&kt[(qk0 + r)*128 + ch*64 + (kc8 ^ ((r & 7) << 3))],
                (unsigned short*)&SL[53248 + it*4096 + w*512]);
  }
  #pragma unroll
  for (int it = 0; it < 4; ++it) {
    const int o = it*4096 + w*512 + lane*8;
    const int dv = o >> 6;
    gload_lds16(&vtg[((size_t)bh*256 + dv)*2048 + c*64 + (kc8 ^ ((dv & 7) << 3))],
                (unsigned short*)&SL[4096 + it*4096 + w*512]);
  }
  #pragma unroll
  for (int it = 0; it < 8; ++it) {
    const int o = it*4096 + w*512 + lane*8;
    const int ch = o >> 14, dv = (o >> 6) & 255;
    gload_lds16(&sst[((size_t)(bh*32 + c)*256 + dv)*128 + ch*64 + (kc8 ^ ((dv & 7) << 3))],
                (unsigned short*)&SL[20480 + it*4096 + w*512]);
  }
  bf16x8 aq[2][4];
  #pragma unroll
  for (int mm = 0; mm < 2; ++mm)
    #pragma unroll
    for (int k4 = 0; k4 < 4; ++k4)
      aq[mm][k4] = *(const bf16x8*)&qt[(qk0 + wr*32 + mm*16 + l15)*128 + k4*32 + lq*8];

  __syncthreads();

  f32x4 accp[2];
  accp[0][0]=0.f; accp[0][1]=0.f; accp[0][2]=0.f; accp[0][3]=0.f;
  accp[1] = accp[0];
  #pragma unroll
  for (int k4 = 0; k4 < 4; ++k4) {
    const int ch = k4 >> 1, k0c = (k4 & 1) * 32;
    const bf16x8 bk = *(const bf16x8*)&SL[53248 + ch*4096 + (wc*16 + l15)*64 + ((k0c + lq*8) ^ key15)];
    accp[0] = __builtin_amdgcn_mfma_f32_16x16x32_bf16(aq[0][k4], bk, accp[0], 0, 0, 0);
    accp[1] = __builtin_amdgcn_mfma_f32_16x16x32_bf16(aq[1][k4], bk, accp[1], 0, 0, 0);
  }
  #pragma unroll
  for (int mm = 0; mm < 2; ++mm)
    #pragma unroll
    for (int i = 0; i < 4; ++i) {
      const int rg = wr*32 + mm*16 + lq*4 + i;
      const int cg = wc*16 + l15;
      SL[rg*64 + (cg ^ ((rg & 7) << 3))] = f2bf((cg <= rg) ? accp[mm][i] : 0.f);
    }
  __syncthreads();

  f32x4 acco[2][4];
  #pragma unroll
  for (int mm = 0; mm < 2; ++mm)
    #pragma unroll
    for (int nn = 0; nn < 4; ++nn) { acco[mm][nn][0]=0.f; acco[mm][nn][1]=0.f; acco[mm][nn][2]=0.f; acco[mm][nn][3]=0.f; }

  #pragma unroll
  for (int t4 = 0; t4 < 2; ++t4) {
    bf16x8 ap[2];
    #pragma unroll
    for (int mm = 0; mm < 2; ++mm) {
      const int r = wr*32 + mm*16 + l15;
      ap[mm] = *(const bf16x8*)&SL[r*64 + ((t4*32 + lq*8) ^ key15)];
    }
    #pragma unroll
    for (int nn = 0; nn < 4; ++nn) {
      const int dv = wc*64 + nn*16 + l15;
      const bf16x8 bv = *(const bf16x8*)&SL[4096 + dv*64 + ((t4*32 + lq*8) ^ key15)];
      acco[0][nn] = __builtin_amdgcn_mfma_f32_16x16x32_bf16(ap[0], bv, acco[0][nn], 0, 0, 0);
      acco[1][nn] = __builtin_amdgcn_mfma_f32_16x16x32_bf16(ap[1], bv, acco[1][nn], 0, 0, 0);
    }
  }
  #pragma unroll
  for (int k4 = 0; k4 < 4; ++k4) {
    const int ch = k4 >> 1, k0c = (k4 & 1) * 32;
    #pragma unroll
    for (int nn = 0; nn < 4; ++nn) {
      const int dv = wc*64 + nn*16 + l15;
      const bf16x8 bs = *(const bf16x8*)&SL[20480 + ch*16384 + dv*64 + ((k0c + lq*8) ^ key15)];
      acco[0][nn] = __builtin_amdgcn_mfma_f32_16x16x32_bf16(aq[0][k4], bs, acco[0][nn], 0, 0, 0);
      acco[1][nn] = __builtin_amdgcn_mfma_f32_16x16x32_bf16(aq[1][k4], bs, acco[1][nn], 0, 0, 0);
    }
  }

  #pragma unroll
  for (int mm = 0; mm < 2; ++mm) {
    float part[4];
    #pragma unroll
    for (int i = 0; i < 4; ++i) {
      float s = 0.f;
      #pragma unroll
      for (int nn = 0; nn < 4; ++nn) s += acco[mm][nn][i]*acco[mm][nn][i];
      s += __shfl_xor(s, 1); s += __shfl_xor(s, 2); s += __shfl_xor(s, 4); s += __shfl_xor(s, 8);
      part[i] = s;
    }
    if (l15 == 0) {
      #pragma unroll
      for (int i = 0; i < 4; ++i)
        atomicAdd(&ssq[wr*32 + mm*16 + lq*4 + i], part[i]);
    }
  }
  __syncthreads();

  #pragma unroll
  for (int mm = 0; mm < 2; ++mm)
    #pragma unroll
    for (int i = 0; i < 4; ++i) {
      const int rg = wr*32 + mm*16 + lq*4 + i;
      const float rs = rsqrtf(ssq[rg] * (1.f/256.f) + 1e-5f);
      const size_t token = tok0 + rg;
      #pragma unroll
      for (int nn = 0; nn < 4; ++nn) {
        const int dv = wc*64 + nn*16 + l15;
        const float gf = bf2f(proj[token*3072 + 2048 + h*256 + dv]);
        const float swv = gf * __builtin_amdgcn_rcpf(1.f + __builtin_amdgcn_exp2f(-1.44269504f*gf));
        og[token*1024 + h*256 + dv] = f2bf(acco[mm][nn][i] * rs * gnw[dv] * swv);
      }
    }
}

extern "C" void kernel_launch(void* const* d_in, const int* in_sizes, int n_in,
                              void* d_out, int out_size, void* d_ws, size_t ws_size,
                              hipStream_t stream)
{
  (void)in_sizes; (void)n_in; (void)out_size; (void)ws_size;
  const float* x    = (const float*)d_in[0];
  const float* ln1g = (const float*)d_in[1];
  const float* ln1b = (const float*)d_in[2];
  const float* Wq   = (const float*)d_in[3];
  const float* Wk   = (const float*)d_in[4];
  const float* Wv   = (const float*)d_in[5];
  const float* Wg   = (const float*)d_in[6];
  const float* Wgk1 = (const float*)d_in[7];
  const float* Wgk2 = (const float*)d_in[8];
  const float* bgk  = (const float*)d_in[9];
  const float* gnw  = (const float*)d_in[10];
  const float* Wo   = (const float*)d_in[11];
  const float* ln2g = (const float*)d_in[12];
  const float* ln2b = (const float*)d_in[13];
  const float* W1   = (const float*)d_in[14];
  const float* b1   = (const float*)d_in[15];
  const float* W2   = (const float*)d_in[16];
  const float* b2   = (const float*)d_in[17];
  float* out = (float*)d_out;
  char* ws = (char*)d_ws;

  // workspace: PROJ now 16384x3072 bf16 (100.7 MB). ZG (1 MB f32) lives in d_out
  // (dead before k_seqstate writes SST there). Other aliases as before.
  u16t*  XN   = (u16t*)(ws + 0);
  u16t*  KTT  = (u16t*)(ws + 0);
  u16t*  OG   = (u16t*)(ws + 0);
  u16t*  WPT  = (u16t*)(ws + 33554432);
  u16t*  WOT  = (u16t*)(ws + 40894464);
  u16t*  W1T  = (u16t*)(ws + 42991616);
  u16t*  W2T  = (u16t*)(ws + 51380224);
  u16t*  PROJ = (u16t*)(ws + 59768832);
  u16t*  QT   = (u16t*)(ws + 177209344);
  u16t*  KT   = (u16t*)(ws + 193986560);
  float* EAC  = (float*)(ws + 210763776);
  u16t*  VT   = (u16t*)(ws + 211288064);
  u16t*  H2   = (u16t*)(ws + 211288064);
  u16t*  HID  = PROJ;
  u16t*  SST  = (u16t*)d_out;
  float* ZG   = (float*)d_out;              // dead before seqstate writes SST

  k_transpose_multi<<<12288, dim3(32,8), 0, stream>>>(Wq, Wk, Wv, Wg, Wo, W1, W2, WPT, WOT, W1T, W2T);

  k_layernorm<<<16384, 256, 0, stream>>>(x, ln1g, ln1b, XN);
  k_zgemm<<<1024, 256, 0, stream>>>(XN, Wgk1, ZG);
  gemm256<0><<<dim3(12,64), 1024, 0, stream>>>(XN, WPT, 3072, 1024, nullptr, PROJ, nullptr, nullptr);
  k_scanprep<<<1024, 128, 0, stream>>>(PROJ, ZG, Wgk2, bgk, QT, KT, EAC);
  k_vtrans<<<dim3(64,12,32), dim3(32,8), 0, stream>>>(PROJ, KT, VT, KTT);
  k_seqstate<<<256, 512, 0, stream>>>(KTT, VT, EAC, SST);
  k_attn_out<<<1024, 512, 0, stream>>>(QT, KT, VT, SST, PROJ, gnw, OG);
  gemm256<1><<<dim3(4,64),  1024, 0, stream>>>(OG, WOT, 1024, 1024, out, nullptr, x, nullptr);   // x1 = o@Wo + x
  k_layernorm<<<16384, 256, 0, stream>>>(out, ln2g, ln2b, H2);
  gemm256<2><<<dim3(16,64), 1024, 0, stream>>>(H2, W1T, 4096, 1024, nullptr, HID, nullptr, b1);  // gelu(h@W1+b1)
  gemm256<3><<<dim3(4,64),  1024, 0, stream>>>(HID, W2T, 1024, 4096, out, nullptr, out, b2);     // out = x1 + hid@W2 + b2
}

// Round 14
// 672.698 us; speedup vs baseline: 1.0601x; 1.0052x over previous
//
#include <hip/hip_runtime.h>
#include <stdint.h>

// GLA block for MI355X (gfx950).
// B=8 S=2048 D=1024 H=4 DK=128 DV=256 CHUNK=64 (32 chunks), MLP_H=4096.
// R14: tail pass. k_attn_out: g-tile staged via global_load_lds (T14 overlap),
// og written through LDS + cooperative coalesced store (was 32 scalar loads +
// 32 scalar stores per thread). k_vtrans -> 64x64 tiles (128B store segments).
// GEMM / seqstate / scanprep unchanged from R13 (GEMMs at m248 shape ceiling).

typedef unsigned short u16t;
typedef __attribute__((ext_vector_type(8))) short bf16x8;
typedef __attribute__((ext_vector_type(4))) float f32x4;
typedef __attribute__((ext_vector_type(4))) unsigned short u16x4;

__device__ __forceinline__ float bf2f(unsigned short u){ union{unsigned int i; float f;} v; v.i=((unsigned int)u)<<16; return v.f; }
__device__ __forceinline__ unsigned short f2bf(float f){ union{unsigned int i; float f;} v; v.f=f; unsigned int r=v.i+0x7FFFu+((v.i>>16)&1u); return (unsigned short)(r>>16); }
__device__ __forceinline__ f32x4 cvt4(u16x4 u){ f32x4 r; r[0]=bf2f(u[0]); r[1]=bf2f(u[1]); r[2]=bf2f(u[2]); r[3]=bf2f(u[3]); return r; }

// fast tanh-GELU (native exp2/rcp); |err| vs exact-erf gelu ~3e-4.
__device__ __forceinline__ float gelu_f(float t){
  const float t3 = t*t*t;
  const float y = 2.3021183f*t + 0.10295465f*t3;
  const float e = __builtin_amdgcn_exp2f(y);
  return t - t*__builtin_amdgcn_rcpf(e + 1.f);
}

__device__ __forceinline__ void gload_lds16(const unsigned short* g, unsigned short* l)
{
  __builtin_amdgcn_global_load_lds(
      (const __attribute__((address_space(1))) unsigned int*)g,
      (__attribute__((address_space(3))) unsigned int*)l,
      16, 0, 0);
}

// ---------------- merged transpose f32 [Kin][N] -> bf16 [N][Kin], 7 weights ----------------
__global__ void k_transpose_multi(const float* __restrict__ Wq, const float* __restrict__ Wk,
                                  const float* __restrict__ Wv, const float* __restrict__ Wg,
                                  const float* __restrict__ Wo, const float* __restrict__ W1,
                                  const float* __restrict__ W2,
                                  unsigned short* __restrict__ WPT, unsigned short* __restrict__ WOT,
                                  unsigned short* __restrict__ W1T, unsigned short* __restrict__ W2T)
{
  __shared__ float tile[32][33];
  int bid = blockIdx.x;
  const float* src; unsigned short* dst; int Kin, N, nx;
  if      (bid < 512)  { src=Wq; dst=WPT;                          Kin=1024; N=512;  nx=16;  }
  else if (bid < 1024) { src=Wk; dst=WPT+(size_t)512*1024;         Kin=1024; N=512;  nx=16;  bid-=512;  }
  else if (bid < 2048) { src=Wv; dst=WPT+(size_t)1024*1024;        Kin=1024; N=1024; nx=32;  bid-=1024; }
  else if (bid < 3072) { src=Wg; dst=WPT+(size_t)2048*1024;        Kin=1024; N=1024; nx=32;  bid-=2048; }
  else if (bid < 4096) { src=Wo; dst=WOT;                          Kin=1024; N=1024; nx=32;  bid-=3072; }
  else if (bid < 8192) { src=W1; dst=W1T;                          Kin=1024; N=4096; nx=128; bid-=4096; }
  else                 { src=W2; dst=W2T;                          Kin=4096; N=1024; nx=32;  bid-=8192; }
  const int n0 = (bid % nx)*32, k0 = (bid / nx)*32;
  const int tx = threadIdx.x, ty = threadIdx.y;
  #pragma unroll
  for (int i = 0; i < 4; ++i)
    tile[ty + i*8][tx] = src[(size_t)(k0 + ty + i*8)*N + n0 + tx];
  __syncthreads();
  #pragma unroll
  for (int i = 0; i < 4; ++i)
    dst[(size_t)(n0 + ty + i*8)*Kin + k0 + tx] = f2bf(tile[tx][ty + i*8]);
}

// ---------------- ZG = XN @ Wgk1 : [16384][16] f32 ----------------
__global__ __launch_bounds__(256) void k_zgemm(const unsigned short* __restrict__ XN,
                                               const float* __restrict__ Wgk1,
                                               float* __restrict__ zg)
{
  __shared__ float Wg1s[128*16];
  __shared__ unsigned short XNs[16*136];
  const int token0 = blockIdx.x * 16;
  const int tid = threadIdx.x;
  const int tt = tid >> 4, j = tid & 15;
  float acc = 0.f;
  for (int cb = 0; cb < 8; ++cb) {
    __syncthreads();
    #pragma unroll
    for (int i = 0; i < 8; ++i)
      Wg1s[i*256 + tid] = Wgk1[(size_t)cb*2048 + i*256 + tid];
    {
      const int r = tid >> 4, cc = (tid & 15) * 8;
      *(u16x4*)&XNs[r*136 + cc]     = *(const u16x4*)&XN[(size_t)(token0 + r)*1024 + cb*128 + cc];
      *(u16x4*)&XNs[r*136 + cc + 4] = *(const u16x4*)&XN[(size_t)(token0 + r)*1024 + cb*128 + cc + 4];
    }
    __syncthreads();
    #pragma unroll 4
    for (int c = 0; c < 128; ++c)
      acc += bf2f(XNs[tt*136 + c]) * Wg1s[c*16 + j];
  }
  zg[(size_t)(token0 + tt)*16 + j] = acc;
}

// ---------------- V/K transpose, 64x64 tiles: proj v-cols -> VT[bh][256][2048]; kt -> KTT[bh][128][2048] ----------------
// grid (32 tt, 6 zz, 32 bh), 256 thr. load: r=tid>>2, c0=(tid&3)*16 (2x u16x8).
// store: d=tid>>2, t0=(tid&3)*16 -> per-4-lane contiguous 128B rows.
__global__ __launch_bounds__(256) void k_vtrans64(const unsigned short* __restrict__ proj,
                                                  const unsigned short* __restrict__ kt,
                                                  unsigned short* __restrict__ vtg,
                                                  unsigned short* __restrict__ ktt)
{
  __shared__ __align__(16) unsigned short tile[64*72];
  const int tt = blockIdx.x, zz = blockIdx.y, bh = blockIdx.z;
  const int b = bh >> 2, h = bh & 3;
  const int tid = threadIdx.x;
  const int r = tid >> 2, c0 = (tid & 3) * 16;

  const unsigned short* src;
  if (zz < 4) src = &proj[((size_t)b*2048 + tt*64 + r)*3072 + 1024 + h*256 + zz*64 + c0];
  else        src = &kt[((size_t)bh*2048 + tt*64 + r)*128 + (zz - 4)*64 + c0];
  *(bf16x8*)&tile[r*72 + c0]     = *(const bf16x8*)&src[0];
  *(bf16x8*)&tile[r*72 + c0 + 8] = *(const bf16x8*)&src[8];
  __syncthreads();

  bf16x8 o0, o1;
  #pragma unroll
  for (int j = 0; j < 8; ++j) {
    ((unsigned short*)&o0)[j] = tile[(c0 + j)*72 + r];
    ((unsigned short*)&o1)[j] = tile[(c0 + 8 + j)*72 + r];
  }
  unsigned short* dst;
  if (zz < 4) dst = &vtg[((size_t)bh*256 + zz*64 + r)*2048 + tt*64 + c0];
  else        dst = &ktt[((size_t)bh*128 + (zz - 4)*64 + r)*2048 + tt*64 + c0];
  *(bf16x8*)&dst[0] = o0;
  *(bf16x8*)&dst[8] = o1;
}

// ---------------- LayerNorm row=1024, f32 in -> bf16 out ----------------
__global__ __launch_bounds__(256) void k_layernorm(const float* __restrict__ x, const float* __restrict__ g,
                                                   const float* __restrict__ b, unsigned short* __restrict__ out)
{
  const int row = blockIdx.x, tid = threadIdx.x;
  const float4 xv = *(const float4*)&x[(size_t)row*1024 + tid*4];
  float s  = xv.x + xv.y + xv.z + xv.w;
  float sq = xv.x*xv.x + xv.y*xv.y + xv.z*xv.z + xv.w*xv.w;
  #pragma unroll
  for (int o = 32; o > 0; o >>= 1) { s += __shfl_xor(s, o); sq += __shfl_xor(sq, o); }
  __shared__ float red[8];
  const int w = tid >> 6;
  if ((tid & 63) == 0) { red[w] = s; red[4 + w] = sq; }
  __syncthreads();
  s  = red[0] + red[1] + red[2] + red[3];
  sq = red[4] + red[5] + red[6] + red[7];
  const float mu = s * (1.f/1024.f);
  const float var = sq * (1.f/1024.f) - mu*mu;
  const float rs = rsqrtf(var + 1e-5f);
  float xe[4] = {xv.x, xv.y, xv.z, xv.w};
  u16x4 o4;
  #pragma unroll
  for (int i = 0; i < 4; ++i) {
    const int c = tid*4 + i;
    o4[i] = f2bf((xe[i] - mu) * rs * g[c] + b[c]);
  }
  *(u16x4*)&out[(size_t)row*1024 + tid*4] = o4;
}

// ---------------- 256x256 16-wave bf16 MFMA GEMM: C = A[M,K] @ Bt[N,K]^T (R11, best) ----------------
template<int EPI>
__global__ __launch_bounds__(1024, 3)
void gemm256(const unsigned short* __restrict__ A, const unsigned short* __restrict__ Bt,
             int N, int K,
             float* outF, unsigned short* outH,
             const float* resid, const float* bias)
{
  __shared__ __align__(16) unsigned short lds[65536];   // 128 KiB
  const int tid = threadIdx.x;
  const int lane = tid & 63, w = tid >> 6;
  const int wr = w >> 2, wc = w & 3;
  const int l15 = lane & 15, lq = lane >> 4;

  const int nwg = gridDim.x * gridDim.y;
  const int bid = blockIdx.y * gridDim.x + blockIdx.x;
  const int q = nwg >> 3, r = nwg & 7;
  const int xcd = bid & 7, lid = bid >> 3;
  const int sw = (xcd < r ? xcd*(q+1) : r*(q+1) + (xcd - r)*q) + lid;
  const int row0 = (sw / gridDim.x) * 256;
  const int col0 = (sw % gridDim.x) * 256;

  const int rA_ = tid >> 3;
  const int cswz = 8 * ((tid & 7) ^ (rA_ & 7));
  const unsigned short* baseA[2];
  const unsigned short* baseB[2];
  #pragma unroll
  for (int h = 0; h < 2; ++h) {
    baseA[h] = A  + (size_t)(row0 + h*128 + rA_) * K + cswz;
    baseB[h] = Bt + (size_t)(col0 + h*128 + rA_) * K + cswz;
  }

  const int NT = K >> 6;

  f32x4 acc[4][4];
  #pragma unroll
  for (int m = 0; m < 4; ++m)
    #pragma unroll
    for (int n = 0; n < 4; ++n) { acc[m][n][0]=0.f; acc[m][n][1]=0.f; acc[m][n][2]=0.f; acc[m][n][3]=0.f; }

  const int carA = (wr >> 1) * 8192;
  const int carB = 16384 + (wc >> 1) * 8192;
  const int rowA = (wr & 1) * 64;
  const int rowB = (wc & 1) * 64;
  const int co = (l15 & 7) * 8;

  #define STAGE4(T)                                                            \
    {                                                                          \
      const int dbase = ((T) & 1) * 32768;                                     \
      const int ktt2 = (T) << 6;                                               \
      gload_lds16(baseA[0] + ktt2, (unsigned short*)&lds[dbase +         w*512]); \
      gload_lds16(baseA[1] + ktt2, (unsigned short*)&lds[dbase +  8192 + w*512]); \
      gload_lds16(baseB[0] + ktt2, (unsigned short*)&lds[dbase + 16384 + w*512]); \
      gload_lds16(baseB[1] + ktt2, (unsigned short*)&lds[dbase + 24576 + w*512]); \
    }

  #define MMAH(BUF, H)                                                         \
    {                                                                          \
      bf16x8 af[4], bfr[4];                                                    \
      _Pragma("unroll")                                                        \
      for (int mm = 0; mm < 4; ++mm)                                           \
        af[mm] = *(const bf16x8*)&lds[(BUF) + carA + (rowA + mm*16 + l15)*64   \
                                      + (((H)*32 + lq*8) ^ co)];               \
      _Pragma("unroll")                                                        \
      for (int nn = 0; nn < 4; ++nn)                                           \
        bfr[nn] = *(const bf16x8*)&lds[(BUF) + carB + (rowB + nn*16 + l15)*64  \
                                       + (((H)*32 + lq*8) ^ co)];              \
      asm volatile("s_waitcnt lgkmcnt(0)" ::: "memory");                       \
      __builtin_amdgcn_sched_barrier(0);                                       \
      if (H) { __builtin_amdgcn_s_barrier(); }  /* WAR: all reads of buf done */ \
      __builtin_amdgcn_s_setprio(1);                                           \
      _Pragma("unroll")                                                        \
      for (int mm = 0; mm < 4; ++mm)                                           \
        _Pragma("unroll")                                                      \
        for (int nn = 0; nn < 4; ++nn)                                         \
          acc[mm][nn] = __builtin_amdgcn_mfma_f32_16x16x32_bf16(               \
              af[mm], bfr[nn], acc[mm][nn], 0, 0, 0);                          \
      __builtin_amdgcn_s_setprio(0);                                           \
    }

  STAGE4(0);
  for (int t = 0; t < NT; ++t) {
    const int buf = (t & 1) * 32768;
    if (t + 1 < NT) {
      STAGE4(t + 1);
      asm volatile("s_waitcnt vmcnt(4)" ::: "memory");
    } else {
      asm volatile("s_waitcnt vmcnt(0)" ::: "memory");
    }
    __builtin_amdgcn_sched_barrier(0);
    __builtin_amdgcn_s_barrier();
    MMAH(buf, 0);
    MMAH(buf, 1);
  }
  #undef STAGE4
  #undef MMAH

  #pragma unroll
  for (int mm = 0; mm < 4; ++mm)
    #pragma unroll
    for (int nn = 0; nn < 4; ++nn)
      #pragma unroll
      for (int ii = 0; ii < 4; ++ii) {
        const int rr = row0 + wr*64 + mm*16 + lq*4 + ii;
        const int cc = col0 + wc*64 + nn*16 + l15;
        const size_t idx = (size_t)rr * N + cc;
        const float v = acc[mm][nn][ii];
        if constexpr (EPI == 0) {
          outH[idx] = f2bf(v);
        } else if constexpr (EPI == 1) {
          outF[idx] = v + resid[idx];
        } else if constexpr (EPI == 2) {
          outH[idx] = f2bf(gelu_f(v + bias[cc]));
        } else {
          outF[idx] = v + bias[cc] + resid[idx];
        }
      }
}

// ---------------- scan prep: z = ZG@Wgk2 + bgk (f32); cumsum gates; write qt/kt bf16, eac f32 ----------------
__global__ __launch_bounds__(128) void k_scanprep(const unsigned short* __restrict__ proj,
                                                  const float* __restrict__ zg,
                                                  const float* __restrict__ Wgk2,
                                                  const float* __restrict__ bgk,
                                                  unsigned short* __restrict__ qt, unsigned short* __restrict__ kt,
                                                  float* __restrict__ eac)
{
  __shared__ float ZGs[1024];   // 64 tokens x 16
  const int c = blockIdx.x & 31, bh = blockIdx.x >> 5;
  const int b = bh >> 2, h = bh & 3;
  const int dk = threadIdx.x;
  const size_t tok0 = (size_t)b*2048 + c*64;
  #pragma unroll
  for (int it = 0; it < 8; ++it)
    ZGs[it*128 + dk] = zg[tok0*16 + it*128 + dk];
  __syncthreads();

  const int col = h*128 + dk;
  const float bg = bgk[col];
  float w2[16];
  #pragma unroll
  for (int r2 = 0; r2 < 16; ++r2) w2[r2] = Wgk2[r2*512 + col];

  float A = 0.f, ea = 1.f;
  for (int t = 0; t < 64; ++t) {
    const size_t prow = (tok0 + t) * 3072;
    const float qv = bf2f(proj[prow + h*128 + dk]);
    const float kv = bf2f(proj[prow + 512 + h*128 + dk]);
    float z = bg;
    #pragma unroll
    for (int r2 = 0; r2 < 16; ++r2) z += ZGs[t*16 + r2] * w2[r2];
    const float az = fabsf(z);
    const float sp = fmaxf(-z, 0.f)
                   + 0.69314718f*__builtin_amdgcn_logf(1.f + __builtin_amdgcn_exp2f(-1.44269504f*az));
    A -= sp * 0.0625f;
    ea = __builtin_amdgcn_exp2f(A * 1.44269504f);
    const float em = __builtin_amdgcn_rcpf(ea);
    const size_t orow = ((size_t)bh*2048 + c*64 + t)*128 + dk;
    qt[orow] = f2bf(qv * ea * 0.08838834764831845f);
    kt[orow] = f2bf(kv * em);
  }
  eac[((size_t)bh*32 + c)*128 + dk] = ea;
}

// ---------------- MFMA chunk-state recurrence; stores S^T[dv][dk] at chunk START ----------------
__global__ __launch_bounds__(512) void k_seqstate(const unsigned short* __restrict__ ktt,
                                                  const unsigned short* __restrict__ vtg,
                                                  const float* __restrict__ eac,
                                                  unsigned short* __restrict__ sst)
{
  __shared__ __align__(16) unsigned short SLq[16384];
  const int bid = blockIdx.x;
  const int bh = bid >> 3, dks = (bid >> 2) & 1, dvs = bid & 3;
  const int tid = threadIdx.x, lane = tid & 63, w = tid >> 6;
  const int wr = w >> 2, wc = w & 3;
  const int l15 = lane & 15, lq = lane >> 4;
  const int kc8 = (lane & 7) * 8;

  #define SSTAGE(C, BUF)                                                        \
    { { const int o = w*512 + lane*8;                                           \
        const int dkl = o >> 6;                                                 \
        gload_lds16(&ktt[((size_t)bh*128 + dks*64 + dkl)*2048 + (C)*64 + (kc8 ^ ((dkl & 7) << 3))], \
                    (unsigned short*)&SLq[(BUF)*8192 + w*512]); }                \
      { const int o = w*512 + lane*8;                                           \
        const int dvl = o >> 6;                                                 \
        gload_lds16(&vtg[((size_t)bh*256 + dvs*64 + dvl)*2048 + (C)*64 + (kc8 ^ ((dvl & 7) << 3))], \
                    (unsigned short*)&SLq[(BUF)*8192 + 4096 + w*512]); } }

  f32x4 acc[2];
  acc[0][0]=0.f; acc[0][1]=0.f; acc[0][2]=0.f; acc[0][3]=0.f;
  acc[1] = acc[0];

  SSTAGE(0, 0);
  asm volatile("s_waitcnt vmcnt(0)" ::: "memory");
  __builtin_amdgcn_sched_barrier(0);
  __builtin_amdgcn_s_barrier();

  for (int c = 0; c < 32; ++c) {
    const int buf = c & 1;
    if (c + 1 < 32) {
      SSTAGE(c + 1, buf ^ 1);
      asm volatile("s_waitcnt vmcnt(2)" ::: "memory");
    } else {
      asm volatile("s_waitcnt vmcnt(0)" ::: "memory");
    }
    __builtin_amdgcn_sched_barrier(0);
    __builtin_amdgcn_s_barrier();

    const size_t srow = (((size_t)bh*32 + c)*256 + dvs*64 + wc*16 + l15)*128;
    #pragma unroll
    for (int mm = 0; mm < 2; ++mm) {
      u16x4 tj;
      tj[0]=f2bf(acc[mm][0]); tj[1]=f2bf(acc[mm][1]); tj[2]=f2bf(acc[mm][2]); tj[3]=f2bf(acc[mm][3]);
      *(u16x4*)&sst[srow + dks*64 + wr*32 + mm*16 + lq*4] = tj;
    }
    f32x4 ev[2];
    #pragma unroll
    for (int mm = 0; mm < 2; ++mm)
      ev[mm] = *(const f32x4*)&eac[(size_t)(bh*32 + c)*128 + dks*64 + wr*32 + mm*16 + lq*4];

    const int base = buf*8192;
    bf16x8 afr[2][2], bfrg[2];
    #pragma unroll
    for (int mm = 0; mm < 2; ++mm) {
      const int rl = wr*32 + mm*16 + l15;
      const int co2 = (rl & 7) << 3;
      afr[mm][0] = *(const bf16x8*)&SLq[base + rl*64 + ((lq*8) ^ co2)];
      afr[mm][1] = *(const bf16x8*)&SLq[base + rl*64 + ((32 + lq*8) ^ co2)];
    }
    {
      const int dvl = wc*16 + l15;
      const int co2 = (dvl & 7) << 3;
      bfrg[0] = *(const bf16x8*)&SLq[base + 4096 + dvl*64 + ((lq*8) ^ co2)];
      bfrg[1] = *(const bf16x8*)&SLq[base + 4096 + dvl*64 + ((32 + lq*8) ^ co2)];
    }
    asm volatile("s_waitcnt lgkmcnt(0)" ::: "memory");
    __builtin_amdgcn_sched_barrier(0);
    #pragma unroll
    for (int k4 = 0; k4 < 2; ++k4)
      #pragma unroll
      for (int mm = 0; mm < 2; ++mm)
        acc[mm] = __builtin_amdgcn_mfma_f32_16x16x32_bf16(afr[mm][k4], bfrg[k4], acc[mm], 0, 0, 0);
    #pragma unroll
    for (int mm = 0; mm < 2; ++mm)
      #pragma unroll
      for (int i = 0; i < 4; ++i)
        acc[mm][i] *= ev[mm][i];
    __builtin_amdgcn_s_barrier();
  }
  #undef SSTAGE
}

// ---------------- fused MFMA attn out: P=tril(QK^T); O=P@V+Q@S0; rmsnorm*g*sig(g) -> og ----------------
// R14: g staged via gload_lds (GS, 32KB); og written via LDS (S-region reuse) +
// cooperative coalesced store.
__global__ __launch_bounds__(512) void k_attn_out(const unsigned short* __restrict__ qt,
                                                  const unsigned short* __restrict__ kt,
                                                  const unsigned short* __restrict__ vtg,
                                                  const unsigned short* __restrict__ sst,
                                                  const unsigned short* __restrict__ proj,
                                                  const float* __restrict__ gnw,
                                                  unsigned short* __restrict__ og)
{
  __shared__ __align__(16) unsigned short SL[61440];
  __shared__ __align__(16) unsigned short GS[16384];   // g tile [64 tok][256 dv]
  __shared__ float ssq[64];
  const int c = blockIdx.x & 31, bh = blockIdx.x >> 5;
  const int b = bh >> 2, h = bh & 3;
  const int tid = threadIdx.x, lane = tid & 63, w = tid >> 6;
  const int wr = w >> 2, wc = w & 3;
  const int l15 = lane & 15, lq = lane >> 4;
  const size_t qk0 = (size_t)bh*2048 + c*64;
  const size_t tok0 = (size_t)b*2048 + c*64;
  const int key15 = (l15 & 7) << 3;

  if (tid < 64) ssq[tid] = 0.f;

  const int kc8 = (lane & 7) * 8;
  #pragma unroll
  for (int it = 0; it < 2; ++it) {
    const int o = it*4096 + w*512 + lane*8;
    const int ch = o >> 12, r = (o >> 6) & 63;
    gload_lds16(&kt[(qk0 + r)*128 + ch*64 + (kc8 ^ ((r & 7) << 3))],
                (unsigned short*)&SL[53248 + it*4096 + w*512]);
  }
  #pragma unroll
  for (int it = 0; it < 4; ++it) {
    const int o = it*4096 + w*512 + lane*8;
    const int dv = o >> 6;
    gload_lds16(&vtg[((size_t)bh*256 + dv)*2048 + c*64 + (kc8 ^ ((dv & 7) << 3))],
                (unsigned short*)&SL[4096 + it*4096 + w*512]);
  }
  #pragma unroll
  for (int it = 0; it < 8; ++it) {
    const int o = it*4096 + w*512 + lane*8;
    const int ch = o >> 14, dv = (o >> 6) & 255;
    gload_lds16(&sst[((size_t)(bh*32 + c)*256 + dv)*128 + ch*64 + (kc8 ^ ((dv & 7) << 3))],
                (unsigned short*)&SL[20480 + it*4096 + w*512]);
  }
  // g tile: GS[r*256 + col] = proj[(tok0+r)*3072 + 2048 + h*256 + col] (linear)
  #pragma unroll
  for (int it = 0; it < 4; ++it) {
    const int e = it*4096 + tid*8;
    gload_lds16(&proj[(tok0 + (e >> 8))*3072 + 2048 + h*256 + (e & 255)],
                (unsigned short*)&GS[it*4096 + w*512]);
  }
  bf16x8 aq[2][4];
  #pragma unroll
  for (int mm = 0; mm < 2; ++mm)
    #pragma unroll
    for (int k4 = 0; k4 < 4; ++k4)
      aq[mm][k4] = *(const bf16x8*)&qt[(qk0 + wr*32 + mm*16 + l15)*128 + k4*32 + lq*8];

  __syncthreads();   // B1: all staging (incl GS) landed

  f32x4 accp[2];
  accp[0][0]=0.f; accp[0][1]=0.f; accp[0][2]=0.f; accp[0][3]=0.f;
  accp[1] = accp[0];
  #pragma unroll
  for (int k4 = 0; k4 < 4; ++k4) {
    const int ch = k4 >> 1, k0c = (k4 & 1) * 32;
    const bf16x8 bk = *(const bf16x8*)&SL[53248 + ch*4096 + (wc*16 + l15)*64 + ((k0c + lq*8) ^ key15)];
    accp[0] = __builtin_amdgcn_mfma_f32_16x16x32_bf16(aq[0][k4], bk, accp[0], 0, 0, 0);
    accp[1] = __builtin_amdgcn_mfma_f32_16x16x32_bf16(aq[1][k4], bk, accp[1], 0, 0, 0);
  }
  #pragma unroll
  for (int mm = 0; mm < 2; ++mm)
    #pragma unroll
    for (int i = 0; i < 4; ++i) {
      const int rg = wr*32 + mm*16 + lq*4 + i;
      const int cg = wc*16 + l15;
      SL[rg*64 + (cg ^ ((rg & 7) << 3))] = f2bf((cg <= rg) ? accp[mm][i] : 0.f);
    }
  __syncthreads();   // B2: Ph ready

  f32x4 acco[2][4];
  #pragma unroll
  for (int mm = 0; mm < 2; ++mm)
    #pragma unroll
    for (int nn = 0; nn < 4; ++nn) { acco[mm][nn][0]=0.f; acco[mm][nn][1]=0.f; acco[mm][nn][2]=0.f; acco[mm][nn][3]=0.f; }

  #pragma unroll
  for (int t4 = 0; t4 < 2; ++t4) {
    bf16x8 ap[2];
    #pragma unroll
    for (int mm = 0; mm < 2; ++mm) {
      const int r = wr*32 + mm*16 + l15;
      ap[mm] = *(const bf16x8*)&SL[r*64 + ((t4*32 + lq*8) ^ key15)];
    }
    #pragma unroll
    for (int nn = 0; nn < 4; ++nn) {
      const int dv = wc*64 + nn*16 + l15;
      const bf16x8 bv = *(const bf16x8*)&SL[4096 + dv*64 + ((t4*32 + lq*8) ^ key15)];
      acco[0][nn] = __builtin_amdgcn_mfma_f32_16x16x32_bf16(ap[0], bv, acco[0][nn], 0, 0, 0);
      acco[1][nn] = __builtin_amdgcn_mfma_f32_16x16x32_bf16(ap[1], bv, acco[1][nn], 0, 0, 0);
    }
  }
  #pragma unroll
  for (int k4 = 0; k4 < 4; ++k4) {
    const int ch = k4 >> 1, k0c = (k4 & 1) * 32;
    #pragma unroll
    for (int nn = 0; nn < 4; ++nn) {
      const int dv = wc*64 + nn*16 + l15;
      const bf16x8 bs = *(const bf16x8*)&SL[20480 + ch*16384 + dv*64 + ((k0c + lq*8) ^ key15)];
      acco[0][nn] = __builtin_amdgcn_mfma_f32_16x16x32_bf16(aq[0][k4], bs, acco[0][nn], 0, 0, 0);
      acco[1][nn] = __builtin_amdgcn_mfma_f32_16x16x32_bf16(aq[1][k4], bs, acco[1][nn], 0, 0, 0);
    }
  }

  #pragma unroll
  for (int mm = 0; mm < 2; ++mm) {
    float part[4];
    #pragma unroll
    for (int i = 0; i < 4; ++i) {
      float s = 0.f;
      #pragma unroll
      for (int nn = 0; nn < 4; ++nn) s += acco[mm][nn][i]*acco[mm][nn][i];
      s += __shfl_xor(s, 1); s += __shfl_xor(s, 2); s += __shfl_xor(s, 4); s += __shfl_xor(s, 8);
      part[i] = s;
    }
    if (l15 == 0) {
      #pragma unroll
      for (int i = 0; i < 4; ++i)
        atomicAdd(&ssq[wr*32 + mm*16 + lq*4 + i], part[i]);
    }
  }
  __syncthreads();   // B3: ssq complete; all MFMA operand reads done

  // gate into OB = SL[20480 .. 36864) (S region ch0, dead now), layout [tok][256]
  #pragma unroll
  for (int mm = 0; mm < 2; ++mm)
    #pragma unroll
    for (int i = 0; i < 4; ++i) {
      const int rg = wr*32 + mm*16 + lq*4 + i;
      const float rs = rsqrtf(ssq[rg] * (1.f/256.f) + 1e-5f);
      #pragma unroll
      for (int nn = 0; nn < 4; ++nn) {
        const int dv = wc*64 + nn*16 + l15;
        const float gf = bf2f(GS[rg*256 + dv]);
        const float swv = gf * __builtin_amdgcn_rcpf(1.f + __builtin_amdgcn_exp2f(-1.44269504f*gf));
        SL[20480 + rg*256 + dv] = f2bf(acco[mm][nn][i] * rs * gnw[dv] * swv);
      }
    }
  __syncthreads();   // B4: OB complete

  // cooperative coalesced store: 64 rows x 256 cols, 4x u16x8 per thread
  {
    const int rr2 = tid >> 3, c8 = (tid & 7) * 8;
    #pragma unroll
    for (int s2 = 0; s2 < 4; ++s2)
      *(bf16x8*)&og[(tok0 + rr2)*1024 + h*256 + c8 + s2*64] =
          *(const bf16x8*)&SL[20480 + rr2*256 + c8 + s2*64];
  }
}

extern "C" void kernel_launch(void* const* d_in, const int* in_sizes, int n_in,
                              void* d_out, int out_size, void* d_ws, size_t ws_size,
                              hipStream_t stream)
{
  (void)in_sizes; (void)n_in; (void)out_size; (void)ws_size;
  const float* x    = (const float*)d_in[0];
  const float* ln1g = (const float*)d_in[1];
  const float* ln1b = (const float*)d_in[2];
  const float* Wq   = (const float*)d_in[3];
  const float* Wk   = (const float*)d_in[4];
  const float* Wv   = (const float*)d_in[5];
  const float* Wg   = (const float*)d_in[6];
  const float* Wgk1 = (const float*)d_in[7];
  const float* Wgk2 = (const float*)d_in[8];
  const float* bgk  = (const float*)d_in[9];
  const float* gnw  = (const float*)d_in[10];
  const float* Wo   = (const float*)d_in[11];
  const float* ln2g = (const float*)d_in[12];
  const float* ln2b = (const float*)d_in[13];
  const float* W1   = (const float*)d_in[14];
  const float* b1   = (const float*)d_in[15];
  const float* W2   = (const float*)d_in[16];
  const float* b2   = (const float*)d_in[17];
  float* out = (float*)d_out;
  char* ws = (char*)d_ws;

  u16t*  XN   = (u16t*)(ws + 0);
  u16t*  KTT  = (u16t*)(ws + 0);
  u16t*  OG   = (u16t*)(ws + 0);
  u16t*  WPT  = (u16t*)(ws + 33554432);
  u16t*  WOT  = (u16t*)(ws + 40894464);
  u16t*  W1T  = (u16t*)(ws + 42991616);
  u16t*  W2T  = (u16t*)(ws + 51380224);
  u16t*  PROJ = (u16t*)(ws + 59768832);
  u16t*  QT   = (u16t*)(ws + 177209344);
  u16t*  KT   = (u16t*)(ws + 193986560);
  float* EAC  = (float*)(ws + 210763776);
  u16t*  VT   = (u16t*)(ws + 211288064);
  u16t*  H2   = (u16t*)(ws + 211288064);
  u16t*  HID  = PROJ;
  u16t*  SST  = (u16t*)d_out;
  float* ZG   = (float*)d_out;              // dead before seqstate writes SST

  k_transpose_multi<<<12288, dim3(32,8), 0, stream>>>(Wq, Wk, Wv, Wg, Wo, W1, W2, WPT, WOT, W1T, W2T);

  k_layernorm<<<16384, 256, 0, stream>>>(x, ln1g, ln1b, XN);
  k_zgemm<<<1024, 256, 0, stream>>>(XN, Wgk1, ZG);
  gemm256<0><<<dim3(12,64), 1024, 0, stream>>>(XN, WPT, 3072, 1024, nullptr, PROJ, nullptr, nullptr);
  k_scanprep<<<1024, 128, 0, stream>>>(PROJ, ZG, Wgk2, bgk, QT, KT, EAC);
  k_vtrans64<<<dim3(32,6,32), 256, 0, stream>>>(PROJ, KT, VT, KTT);
  k_seqstate<<<256, 512, 0, stream>>>(KTT, VT, EAC, SST);
  k_attn_out<<<1024, 512, 0, stream>>>(QT, KT, VT, SST, PROJ, gnw, OG);
  gemm256<1><<<dim3(4,64),  1024, 0, stream>>>(OG, WOT, 1024, 1024, out, nullptr, x, nullptr);   // x1 = o@Wo + x
  k_layernorm<<<16384, 256, 0, stream>>>(out, ln2g, ln2b, H2);
  gemm256<2><<<dim3(16,64), 1024, 0, stream>>>(H2, W1T, 4096, 1024, nullptr, HID, nullptr, b1);  // gelu(h@W1+b1)
  gemm256<3><<<dim3(4,64),  1024, 0, stream>>>(HID, W2T, 1024, 4096, out, nullptr, out, b2);     // out = x1 + hid@W2 + b2
}